// Round 2
// baseline (145.695 us; speedup 1.0000x reference)
//
#include <hip/hip_runtime.h>

// out[b, i, j] = x[b, i + j];  B=128, L=8192, W=31, n_win = L - 30 = 8162.
// Pure write-BW-bound broadcast. Flat output treated as float4 stream.

constexpr int B_   = 128;
constexpr int L_   = 8192;
constexpr int W_   = 31;
constexpr int NWIN = L_ - (W_ - 1);          // 8162
constexpr int PERB = NWIN * W_;              // 253022 floats per batch row
constexpr int TOTAL = B_ * PERB;             // 32,386,816 (divisible by 4)
constexpr int NVEC  = TOTAL / 4;             // 8,096,704 float4 stores
constexpr int BLOCK = 256;
constexpr int GRID  = (NVEC + BLOCK - 1) / BLOCK;  // 31,628 (ceil-div; tail guarded)

__global__ __launch_bounds__(BLOCK) void unfold_kernel(const float* __restrict__ x,
                                                       float* __restrict__ out) {
    int t = blockIdx.x * BLOCK + threadIdx.x;   // float4 index
    if (t >= NVEC) return;
    int o = t * 4;                              // flat output element index

    float v[4];
#pragma unroll
    for (int k = 0; k < 4; ++k) {
        int oo = o + k;
        int b  = oo / PERB;          // magic-mul
        int q  = oo - b * PERB;
        int i  = q / W_;             // magic-mul
        int j  = q - i * W_;
        v[k] = x[b * L_ + i + j];
    }
    float4 f4;
    f4.x = v[0]; f4.y = v[1]; f4.z = v[2]; f4.w = v[3];
    reinterpret_cast<float4*>(out)[t] = f4;
}

extern "C" void kernel_launch(void* const* d_in, const int* in_sizes, int n_in,
                              void* d_out, int out_size, void* d_ws, size_t ws_size,
                              hipStream_t stream) {
    const float* x = (const float*)d_in[0];
    float* out = (float*)d_out;
    unfold_kernel<<<GRID, BLOCK, 0, stream>>>(x, out);
}